// Round 15
// baseline (2457.114 us; speedup 1.0000x reference)
//
#include <hip/hip_runtime.h>
#include <stdint.h>

#define TT 512
#define BB 64
#define DD 1024
#define HH 1024

typedef float  f32x4   __attribute__((ext_vector_type(4)));
typedef float  float4v __attribute__((ext_vector_type(4)));
typedef short  bf16x8  __attribute__((ext_vector_type(8)));
typedef short  short4v __attribute__((ext_vector_type(4)));
typedef unsigned long long u64;

__device__ __forceinline__ short f2bf(float x) {
  uint32_t u = __builtin_bit_cast(uint32_t, x);
  u += 0x7fffu + ((u >> 16) & 1u);   // RNE to bf16
  return (short)(u >> 16);
}
__device__ __forceinline__ float bf2f(short s) {
  uint32_t u = ((uint32_t)(uint16_t)s) << 16;
  return __builtin_bit_cast(float, u);
}

// MALL-coherent (agent-scope, L1/L2-bypassing) accesses — no cache flushes.
__device__ __forceinline__ u64 aload(const u64* p) {
  return __hip_atomic_load(p, __ATOMIC_RELAXED, __HIP_MEMORY_SCOPE_AGENT);
}
__device__ __forceinline__ void astore(u64* p, u64 v) {
  __hip_atomic_store(p, v, __ATOMIC_RELAXED, __HIP_MEMORY_SCOPE_AGENT);
}
__device__ __forceinline__ float aloadf(const float* p) {
  return __hip_atomic_load(p, __ATOMIC_RELAXED, __HIP_MEMORY_SCOPE_AGENT);
}
__device__ __forceinline__ void astoref(float* p, float v) {
  __hip_atomic_store(p, v, __ATOMIC_RELAXED, __HIP_MEMORY_SCOPE_AGENT);
}

union HU { u64 q[2]; bf16x8 v; };

// ---------------- W transpose + hi/lo split: W[k][n] f32 -> Wt_hi/lo[n][k] bf16 ----
__global__ __launch_bounds__(256) void k_wsplit(
    const float* __restrict__ Wih, const float* __restrict__ Whh,
    short* __restrict__ ih_hi, short* __restrict__ ih_lo,
    short* __restrict__ hh_hi, short* __restrict__ hh_lo)
{
  __shared__ float tile[64][65];
  int bid = blockIdx.x;
  int z = bid >> 8;              // 0: W_ih, 1: W_hh
  int tt = bid & 255;
  int tk = tt >> 4, tn = tt & 15;
  const float* __restrict__ src = z ? Whh : Wih;
  short* __restrict__ dhi = z ? hh_hi : ih_hi;
  short* __restrict__ dlo = z ? hh_lo : ih_lo;
  int k0 = tk * 64, n0 = tn * 64;
  int tid = threadIdx.x;
  #pragma unroll
  for (int i = 0; i < 4; ++i) {
    int idx = tid + i * 256;
    int r = idx >> 4, c4 = (idx & 15) * 4;
    float4v v = *reinterpret_cast<const float4v*>(&src[(size_t)(k0 + r) * HH + n0 + c4]);
    tile[r][c4 + 0] = v[0]; tile[r][c4 + 1] = v[1];
    tile[r][c4 + 2] = v[2]; tile[r][c4 + 3] = v[3];
  }
  __syncthreads();
  #pragma unroll
  for (int i = 0; i < 4; ++i) {
    int idx = tid + i * 256;
    int n = idx >> 4, kq = (idx & 15) * 4;
    short4v vh, vl;
    #pragma unroll
    for (int j = 0; j < 4; ++j) {
      float x = tile[kq + j][n];
      short h = f2bf(x);
      vh[j] = h;
      vl[j] = f2bf(x - bf2f(h));
    }
    *reinterpret_cast<short4v*>(&dhi[(size_t)(n0 + n) * 1024 + k0 + kq]) = vh;
    *reinterpret_cast<short4v*>(&dlo[(size_t)(n0 + n) * 1024 + k0 + kq]) = vl;
  }
}

// ---------------- pack init_state into h plane layout [g][kb128][row16][8] --------
__global__ __launch_bounds__(256) void k_init_h(
    const float* __restrict__ init, short* __restrict__ hhi)
{
  int i = blockIdx.x * 256 + threadIdx.x;   // 0..65535
  float v = init[i];
  int b = i >> 10, n = i & 1023;
  int g = b >> 4, row = b & 15, kb = n >> 3, e = n & 7;
  size_t off = ((size_t)(g * 128 + kb) * 16 + row) * 8 + e;
  hhi[off] = f2bf(v);
}

// ---------------- fused kernel: blocks 0..63 = recurrence, 64.. = xp GEMM --------
// R14 chassis; ONE lever: 16 WGs x 64 cols per group (was 32 x 32) -> h
// broadcast duplication halved (4 -> 2 MB/step). Enabled by W bf16-only in
// LDS (64 cols x 1032 = 132 KB). All 4 waves reduce+tanh+wave-local pack
// their own 16-col tile; 3 barriers/step; 16 flags/group; fast tanh.
__global__ __launch_bounds__(256) void k_fused(
    const float* __restrict__ A,             // input [T*B, D]
    const short* __restrict__ ih_hi, const short* __restrict__ ih_lo,
    const float* __restrict__ bias,
    const short* __restrict__ whh_hi,
    float* __restrict__ xp,
    u64* __restrict__ hhi64,
    unsigned* __restrict__ flags, int* __restrict__ xpcnt,
    float* __restrict__ out)
{
  __shared__ __align__(16) char smem[148480];
  int bid = blockIdx.x;
  int tid = threadIdx.x;
  int lane = tid & 63, wid = tid >> 6;

  if (bid < 64) {
    // =================== RNN part ===========================================
    short* Wh = (short*)smem;                       // [64 cols][1032] bf16
    float* red = (float*)(smem + 132096);           // 12 slots x 64 x 4 f32
    float* stage = (float*)(smem + 144384);         // [row16][col64] f32

    int g = bid & 3;               // batch-row group: rows g*16..+16
    int w = bid >> 2;              // 0..15: 64-col slice
    int c0 = w * 64;
    int kh = wid;                  // wave = K-quarter (8 ksteps), all 4 nt
    int lr = lane & 15, lk = lane >> 4;

    // fill W slice (once) — col-major padded layout, hi plane only
    {
      int c = tid >> 2, seg = tid & 3;    // c 0..63, seg 0..3 (256 k each)
      #pragma unroll
      for (int j = 0; j < 32; ++j) {
        int k = seg * 256 + j * 8;
        *reinterpret_cast<bf16x8*>(&Wh[c * 1032 + k]) =
            *reinterpret_cast<const bf16x8*>(&whh_hi[(size_t)(c0 + c) * 1024 + k]);
      }
    }
    __syncthreads();

    unsigned* gflags = flags + g * 256;   // 16 slots x 16 u32 (64B spacing)
    for (int t = 0; t < TT; ++t) {
      bool gate = (t & 63) == 0;
      float xpv[4];
      // non-gate steps: xp prefetch before the poll (each wave its nt=wid tile)
      if (!gate) {
        #pragma unroll
        for (int r = 0; r < 4; ++r) {
          int brow = g * 16 + lk * 4 + r;
          xpv[r] = aloadf(&xp[((size_t)t * 64 + brow) * 1024 + c0 + wid * 16 + lr]);
        }
      }
      if (gate && tid == 0) {   // chunk gate: xp for t..t+63 fully stored
        while (__hip_atomic_load(&xpcnt[t >> 6], __ATOMIC_RELAXED,
                                 __HIP_MEMORY_SCOPE_AGENT) < 256)
          __builtin_amdgcn_s_sleep(1);
      }
      if (t > 0 && wid == 0) {
        // wave-0 poll: 16 lanes read this group's 16 per-WG flags
        int ok;
        do {
          unsigned v = (lane < 16)
              ? __hip_atomic_load(&gflags[lane * 16], __ATOMIC_RELAXED,
                                  __HIP_MEMORY_SCOPE_AGENT)
              : 0xffffffffu;
          ok = (lane < 16) ? ((int)v >= t) : 1;
        } while (!__all(ok));
      }
      __syncthreads();   // release: h(t) visible (and, on gate steps, xp chunk)
      if (gate) {
        #pragma unroll
        for (int r = 0; r < 4; ++r) {
          int brow = g * 16 + lk * 4 + r;
          xpv[r] = aloadf(&xp[((size_t)t * 64 + brow) * 1024 + c0 + wid * 16 + lr]);
        }
      }

      const u64* hhq = hhi64 + (size_t)(t & 1) * 16384;
      f32x4 acc[4][2];
      #pragma unroll
      for (int nt = 0; nt < 4; ++nt)
        #pragma unroll
        for (int p = 0; p < 2; ++p) {
          acc[nt][p][0] = 0.f; acc[nt][p][1] = 0.f;
          acc[nt][p][2] = 0.f; acc[nt][p][3] = 0.f;
        }
      #pragma unroll
      for (int ks = 0; ks < 8; ++ks) {
        int kstep = kh * 8 + ks;
        int kb = kstep * 4 + lk;
        size_t ai = ((size_t)(g * 128 + kb) * 16 + lr) * 2;
        HU ua;
        ua.q[0] = aload(hhq + ai); ua.q[1] = aload(hhq + ai + 1);
        int p = ks & 1;
        #pragma unroll
        for (int nt = 0; nt < 4; ++nt) {
          int boff = (nt * 16 + lr) * 1032 + kstep * 32 + lk * 8;
          bf16x8 bh = *reinterpret_cast<const bf16x8*>(&Wh[boff]);
          acc[nt][p] = __builtin_amdgcn_mfma_f32_16x16x32_bf16(ua.v, bh, acc[nt][p], 0, 0, 0);
        }
      }
      // publish foreign partials: receiver r gets senders {0..3}\{r} in slots
      // r*3 + (sender<r ? sender : sender-1)
      f32x4 s[4];
      #pragma unroll
      for (int nt = 0; nt < 4; ++nt)
        #pragma unroll
        for (int r = 0; r < 4; ++r)
          s[nt][r] = acc[nt][0][r] + acc[nt][1][r];
      #pragma unroll
      for (int r = 0; r < 4; ++r) {
        if (r != wid) {
          int slot = r * 3 + (wid < r ? wid : wid - 1);
          *reinterpret_cast<f32x4*>(&red[(slot * 64 + lane) * 4]) = s[r];
        }
      }
      __syncthreads();                       // barrier1: red ready
      {
        // wave wid reduces its own nt=wid tile + fast tanh -> stage
        f32x4 acc_s = s[wid];
        #pragma unroll
        for (int j = 0; j < 3; ++j) {
          f32x4 rv = *reinterpret_cast<const f32x4*>(&red[((wid * 3 + j) * 64 + lane) * 4]);
          #pragma unroll
          for (int r = 0; r < 4; ++r) acc_s[r] += rv[r];
        }
        #pragma unroll
        for (int r = 0; r < 4; ++r) {
          float x = acc_s[r] + xpv[r];
          float ex = __expf(2.0f * x);       // tanh = 1 - 2/(e^2x + 1)
          stage[(lk * 4 + r) * 64 + wid * 16 + lr] = 1.0f - 2.0f / (ex + 1.0f);
        }
        // wave-local transposed pack (own 16-col tile; intra-wave LDS order)
        asm volatile("s_waitcnt lgkmcnt(0)" ::: "memory");
        int row = lane & 15, q = lane >> 4;
        int lc = wid * 16 + q * 4;           // col base within 64-col slice
        float4v sv = *reinterpret_cast<const float4v*>(&stage[row * 64 + lc]);
        short h0 = f2bf(sv[0]), h1 = f2bf(sv[1]), h2 = f2bf(sv[2]), h3 = f2bf(sv[3]);
        u64 hw = (u64)(uint16_t)h0 | ((u64)(uint16_t)h1 << 16) |
                 ((u64)(uint16_t)h2 << 32) | ((u64)(uint16_t)h3 << 48);
        u64* nhq = hhi64 + (size_t)((t + 1) & 1) * 16384;
        size_t off = ((size_t)(g * 128 + w * 8 + (lc >> 3)) * 16 + row) * 2 + ((lc >> 2) & 1);
        astore(nhq + off, hw);
        if (t == TT - 1) {
          size_t o = (size_t)(g * 16 + row) * 1024 + c0 + lc;
          *reinterpret_cast<float4v*>(&out[o]) = sv;
          *reinterpret_cast<float4v*>(&out[65536 + o]) = sv;
        }
      }
      // release: drain sc1 stores, barrier, then ONE flag STORE per WG (no RMW)
      asm volatile("s_waitcnt vmcnt(0)" ::: "memory");
      __syncthreads();
      if (tid == 0)
        __hip_atomic_store(&gflags[w * 16], (unsigned)(t + 1), __ATOMIC_RELAXED,
                           __HIP_MEMORY_SCOPE_AGENT);
    }
  } else {
    // =================== xp GEMM part: [32768 x 1024] = A @ W_ih + bias ======
    short* Ah = (short*)smem;            // 4096 shorts
    short* Al = (short*)(smem + 8192);
    short* Bh = (short*)(smem + 16384);
    short* Bl = (short*)(smem + 24576);

    int b2 = bid - 64;
    int nb = b2 & 7, mb = b2 >> 3;       // t-major: mb = 2 timesteps
    size_t m0 = (size_t)mb * 128;
    int n0 = nb * 128;
    int wm = wid >> 1, wn = wid & 1;
    int lr = lane & 15, lk = lane >> 4;

    f32x4 acc[4][4];
    #pragma unroll
    for (int mt = 0; mt < 4; ++mt)
      #pragma unroll
      for (int nt = 0; nt < 4; ++nt) {
        acc[mt][nt][0] = 0.f; acc[mt][nt][1] = 0.f;
        acc[mt][nt][2] = 0.f; acc[mt][nt][3] = 0.f;
      }

    for (int kt = 0; kt < 32; ++kt) {
      int k0 = kt * 32;
      __syncthreads();
      #pragma unroll
      for (int i = 0; i < 4; ++i) {
        int idx = tid + i * 256;
        int r = idx >> 3, q = idx & 7;
        float4v v = *reinterpret_cast<const float4v*>(&A[(m0 + r) * 1024 + k0 + q * 4]);
        short4v vh, vl;
        #pragma unroll
        for (int j = 0; j < 4; ++j) {
          short h = f2bf(v[j]);
          vh[j] = h;
          vl[j] = f2bf(v[j] - bf2f(h));
        }
        int off = ((q >> 1) * 128 + r) * 8 + (q & 1) * 4;
        *reinterpret_cast<short4v*>(&Ah[off]) = vh;
        *reinterpret_cast<short4v*>(&Al[off]) = vl;
      }
      {
        int n = tid >> 1, half = tid & 1;
        size_t gb = (size_t)(n0 + n) * 1024 + k0 + half * 16;
        bf16x8 h0 = *reinterpret_cast<const bf16x8*>(&ih_hi[gb]);
        bf16x8 h1 = *reinterpret_cast<const bf16x8*>(&ih_hi[gb + 8]);
        bf16x8 l0 = *reinterpret_cast<const bf16x8*>(&ih_lo[gb]);
        bf16x8 l1 = *reinterpret_cast<const bf16x8*>(&ih_lo[gb + 8]);
        int kb = half * 2;
        *reinterpret_cast<bf16x8*>(&Bh[(kb * 128 + n) * 8]) = h0;
        *reinterpret_cast<bf16x8*>(&Bh[((kb + 1) * 128 + n) * 8]) = h1;
        *reinterpret_cast<bf16x8*>(&Bl[(kb * 128 + n) * 8]) = l0;
        *reinterpret_cast<bf16x8*>(&Bl[((kb + 1) * 128 + n) * 8]) = l1;
      }
      __syncthreads();

      bf16x8 a_h[4], a_l[4], b_h[4], b_l[4];
      #pragma unroll
      for (int mt = 0; mt < 4; ++mt) {
        int off = (lk * 128 + wm * 64 + mt * 16 + lr) * 8;
        a_h[mt] = *reinterpret_cast<const bf16x8*>(&Ah[off]);
        a_l[mt] = *reinterpret_cast<const bf16x8*>(&Al[off]);
      }
      #pragma unroll
      for (int nt = 0; nt < 4; ++nt) {
        int off = (lk * 128 + wn * 64 + nt * 16 + lr) * 8;
        b_h[nt] = *reinterpret_cast<const bf16x8*>(&Bh[off]);
        b_l[nt] = *reinterpret_cast<const bf16x8*>(&Bl[off]);
      }
      #pragma unroll
      for (int mt = 0; mt < 4; ++mt)
        #pragma unroll
        for (int nt = 0; nt < 4; ++nt) {
          acc[mt][nt] = __builtin_amdgcn_mfma_f32_16x16x32_bf16(a_h[mt], b_h[nt], acc[mt][nt], 0, 0, 0);
          acc[mt][nt] = __builtin_amdgcn_mfma_f32_16x16x32_bf16(a_h[mt], b_l[nt], acc[mt][nt], 0, 0, 0);
          acc[mt][nt] = __builtin_amdgcn_mfma_f32_16x16x32_bf16(a_l[mt], b_h[nt], acc[mt][nt], 0, 0, 0);
        }
    }
    // epilogue: agent-scope stores (MALL write-through), drain + chunk signal.
    #pragma unroll
    for (int nt = 0; nt < 4; ++nt) {
      int col = n0 + wn * 64 + nt * 16 + lr;
      float bv = bias[col];
      #pragma unroll
      for (int mt = 0; mt < 4; ++mt)
        #pragma unroll
        for (int r = 0; r < 4; ++r) {
          size_t row = m0 + wm * 64 + mt * 16 + lk * 4 + r;
          astoref(&xp[row * 1024 + col], acc[mt][nt][r] + bv);
        }
    }
    asm volatile("s_waitcnt vmcnt(0)" ::: "memory");
    __syncthreads();
    if (tid == 0)
      __hip_atomic_fetch_add(&xpcnt[mb >> 5], 1, __ATOMIC_RELAXED,
                             __HIP_MEMORY_SCOPE_AGENT);
  }
}

extern "C" void kernel_launch(void* const* d_in, const int* in_sizes, int n_in,
                              void* d_out, int out_size, void* d_ws, size_t ws_size,
                              hipStream_t stream) {
  (void)in_sizes; (void)n_in; (void)out_size; (void)ws_size;
  const float* input      = (const float*)d_in[0];
  const float* init_state = (const float*)d_in[1];
  const float* W_ih       = (const float*)d_in[2];
  const float* W_hh       = (const float*)d_in[3];
  const float* bias       = (const float*)d_in[4];
  float* out = (float*)d_out;

  char* ws = (char*)d_ws;
  float* xp = (float*)ws;
  size_t off = (size_t)TT * BB * HH * 4;                 // 134.2 MB x_proj
  short* ih_hi = (short*)(ws + off); off += (size_t)DD * HH * 2;
  short* ih_lo = (short*)(ws + off); off += (size_t)DD * HH * 2;
  short* hh_hi = (short*)(ws + off); off += (size_t)HH * HH * 2;
  short* hh_lo = (short*)(ws + off); off += (size_t)HH * HH * 2;
  u64*   h_hi  = (u64*)(ws + off);   off += (size_t)2 * 16384 * 8;
  unsigned* flags = (unsigned*)(ws + off); off += (size_t)1024 * 4;  // 4 groups x 16 x 16
  int*   xpcnt = (int*)(ws + off);   off += (size_t)16 * 4;

  hipMemsetAsync(flags, 0, 1024 * 4 + 16 * 4, stream);
  k_wsplit<<<512, 256, 0, stream>>>(W_ih, W_hh, ih_hi, ih_lo, hh_hi, hh_lo);
  k_init_h<<<256, 256, 0, stream>>>(init_state, (short*)h_hi);
  k_fused<<<2112, 256, 0, stream>>>(input, ih_hi, ih_lo, bias, hh_hi,
                                    xp, h_hi, flags, xpcnt, out);
}

// Round 16
// 1694.278 us; speedup vs baseline: 1.4502x; 1.4502x over previous
//
#include <hip/hip_runtime.h>
#include <stdint.h>

#define TT 512
#define BB 64
#define DD 1024
#define HH 1024

typedef float  f32x4   __attribute__((ext_vector_type(4)));
typedef float  float4v __attribute__((ext_vector_type(4)));
typedef short  bf16x8  __attribute__((ext_vector_type(8)));
typedef short  short4v __attribute__((ext_vector_type(4)));
typedef unsigned long long u64;

__device__ __forceinline__ short f2bf(float x) {
  uint32_t u = __builtin_bit_cast(uint32_t, x);
  u += 0x7fffu + ((u >> 16) & 1u);   // RNE to bf16
  return (short)(u >> 16);
}
__device__ __forceinline__ float bf2f(short s) {
  uint32_t u = ((uint32_t)(uint16_t)s) << 16;
  return __builtin_bit_cast(float, u);
}

// MALL-coherent (agent-scope, L1/L2-bypassing) accesses — no cache flushes.
__device__ __forceinline__ u64 aload(const u64* p) {
  return __hip_atomic_load(p, __ATOMIC_RELAXED, __HIP_MEMORY_SCOPE_AGENT);
}
__device__ __forceinline__ void astore(u64* p, u64 v) {
  __hip_atomic_store(p, v, __ATOMIC_RELAXED, __HIP_MEMORY_SCOPE_AGENT);
}
__device__ __forceinline__ float aloadf(const float* p) {
  return __hip_atomic_load(p, __ATOMIC_RELAXED, __HIP_MEMORY_SCOPE_AGENT);
}
__device__ __forceinline__ void astoref(float* p, float v) {
  __hip_atomic_store(p, v, __ATOMIC_RELAXED, __HIP_MEMORY_SCOPE_AGENT);
}

union HU { u64 q[2]; bf16x8 v; };

// ---------------- W transpose + hi/lo split: W[k][n] f32 -> Wt_hi/lo[n][k] bf16 ----
__global__ __launch_bounds__(256) void k_wsplit(
    const float* __restrict__ Wih, const float* __restrict__ Whh,
    short* __restrict__ ih_hi, short* __restrict__ ih_lo,
    short* __restrict__ hh_hi, short* __restrict__ hh_lo)
{
  __shared__ float tile[64][65];
  int bid = blockIdx.x;
  int z = bid >> 8;              // 0: W_ih, 1: W_hh
  int tt = bid & 255;
  int tk = tt >> 4, tn = tt & 15;
  const float* __restrict__ src = z ? Whh : Wih;
  short* __restrict__ dhi = z ? hh_hi : ih_hi;
  short* __restrict__ dlo = z ? hh_lo : ih_lo;
  int k0 = tk * 64, n0 = tn * 64;
  int tid = threadIdx.x;
  #pragma unroll
  for (int i = 0; i < 4; ++i) {
    int idx = tid + i * 256;
    int r = idx >> 4, c4 = (idx & 15) * 4;
    float4v v = *reinterpret_cast<const float4v*>(&src[(size_t)(k0 + r) * HH + n0 + c4]);
    tile[r][c4 + 0] = v[0]; tile[r][c4 + 1] = v[1];
    tile[r][c4 + 2] = v[2]; tile[r][c4 + 3] = v[3];
  }
  __syncthreads();
  #pragma unroll
  for (int i = 0; i < 4; ++i) {
    int idx = tid + i * 256;
    int n = idx >> 4, kq = (idx & 15) * 4;
    short4v vh, vl;
    #pragma unroll
    for (int j = 0; j < 4; ++j) {
      float x = tile[kq + j][n];
      short h = f2bf(x);
      vh[j] = h;
      vl[j] = f2bf(x - bf2f(h));
    }
    *reinterpret_cast<short4v*>(&dhi[(size_t)(n0 + n) * 1024 + k0 + kq]) = vh;
    *reinterpret_cast<short4v*>(&dlo[(size_t)(n0 + n) * 1024 + k0 + kq]) = vl;
  }
}

// ---------------- pack init_state into h plane layout [g][kb128][row16][8] --------
__global__ __launch_bounds__(256) void k_init_h(
    const float* __restrict__ init, short* __restrict__ hhi)
{
  int i = blockIdx.x * 256 + threadIdx.x;   // 0..65535
  float v = init[i];
  int b = i >> 10, n = i & 1023;
  int g = b >> 4, row = b & 15, kb = n >> 3, e = n & 7;
  size_t off = ((size_t)(g * 128 + kb) * 16 + row) * 8 + e;
  hhi[off] = f2bf(v);
}

// ---------------- fused kernel: blocks 0..127 = recurrence, 128.. = xp GEMM ------
// R14 chassis verbatim; ONE factor changed: W_hh bf16-only in LDS (no lo
// plane) -> 8 MFMAs + 8 W-LDS reads per wave per step (was 16+16). h stays
// bf16-only (R14). Two independent rounding sources (~7.8e-3 W-only, ~6.2e-3
// h-only measured) -> est ~1e-2 combined, under the 2e-2 threshold.
__global__ __launch_bounds__(256) void k_fused(
    const float* __restrict__ A,             // input [T*B, D]
    const short* __restrict__ ih_hi, const short* __restrict__ ih_lo,
    const float* __restrict__ bias,
    const short* __restrict__ whh_hi,
    float* __restrict__ xp,
    u64* __restrict__ hhi64,
    unsigned* __restrict__ flags, int* __restrict__ xpcnt,
    float* __restrict__ out)
{
  __shared__ __align__(16) char smem[140288];   // keep R14 size -> same occupancy
  int bid = blockIdx.x;
  int tid = threadIdx.x;
  int lane = tid & 63, wid = tid >> 6;

  if (bid < 128) {
    // =================== RNN part (R14 chassis, W hi-only) ===================
    short* Wh = (short*)smem;                       // [32 cols][1032] bf16
    float* red = (float*)(smem + 66048);            // 6*64*4 floats
    float* stage = (float*)(smem + 72192);          // 512 floats

    int g = bid & 3;               // batch-row group: rows g*16..+16
    int w = bid >> 2;              // 0..31: column slice
    int c0 = w * 32;
    int kh = wid;                  // wave = K-quarter (8 ksteps), both nt
    int lr = lane & 15, lk = lane >> 4;

    // fill W slice (once) — col-major padded layout, hi plane only
    {
      int c = tid >> 3, seg = tid & 7;
      #pragma unroll
      for (int j = 0; j < 16; ++j) {
        int k = seg * 128 + j * 8;
        *reinterpret_cast<bf16x8*>(&Wh[c * 1032 + k]) =
            *reinterpret_cast<const bf16x8*>(&whh_hi[(size_t)(c0 + c) * 1024 + k]);
      }
    }
    __syncthreads();

    unsigned* gflags = flags + g * 512;   // 32 slots x 16 u32 (64B spacing)
    for (int t = 0; t < TT; ++t) {
      bool gate = (t & 63) == 0;
      float xpv[4];
      // non-gate steps: xp prefetch before the poll (R7 order)
      if (!gate && wid < 2) {
        #pragma unroll
        for (int r = 0; r < 4; ++r) {
          int brow = g * 16 + lk * 4 + r;
          xpv[r] = aloadf(&xp[((size_t)t * 64 + brow) * 1024 + c0 + wid * 16 + lr]);
        }
      }
      if (gate && tid == 0) {   // chunk gate: xp for t..t+63 fully stored
        while (__hip_atomic_load(&xpcnt[t >> 6], __ATOMIC_RELAXED,
                                 __HIP_MEMORY_SCOPE_AGENT) < 256)
          __builtin_amdgcn_s_sleep(1);
      }
      if (t > 0 && wid == 0) {
        // wave-0 parallel poll: 32 lanes read 32 per-WG flags (distinct lines)
        int ok;
        do {
          unsigned v = (lane < 32)
              ? __hip_atomic_load(&gflags[lane * 16], __ATOMIC_RELAXED,
                                  __HIP_MEMORY_SCOPE_AGENT)
              : 0xffffffffu;
          ok = (lane < 32) ? ((int)v >= t) : 1;
        } while (!__all(ok));
      }
      __syncthreads();   // release: h(t) visible (and, on gate steps, xp chunk)
      if (gate && wid < 2) {
        #pragma unroll
        for (int r = 0; r < 4; ++r) {
          int brow = g * 16 + lk * 4 + r;
          xpv[r] = aloadf(&xp[((size_t)t * 64 + brow) * 1024 + c0 + wid * 16 + lr]);
        }
      }

      const u64* hhq = hhi64 + (size_t)(t & 1) * 16384;
      f32x4 acc[2][2];
      #pragma unroll
      for (int nt = 0; nt < 2; ++nt)
        #pragma unroll
        for (int p = 0; p < 2; ++p) {
          acc[nt][p][0] = 0.f; acc[nt][p][1] = 0.f;
          acc[nt][p][2] = 0.f; acc[nt][p][3] = 0.f;
        }
      #pragma unroll
      for (int ks = 0; ks < 8; ++ks) {
        int kstep = kh * 8 + ks;
        int kb = kstep * 4 + lk;
        size_t ai = ((size_t)(g * 128 + kb) * 16 + lr) * 2;
        HU ua;
        ua.q[0] = aload(hhq + ai); ua.q[1] = aload(hhq + ai + 1);
        int p = ks & 1;
        #pragma unroll
        for (int nt = 0; nt < 2; ++nt) {
          int boff = (nt * 16 + lr) * 1032 + kstep * 32 + lk * 8;
          bf16x8 bh = *reinterpret_cast<const bf16x8*>(&Wh[boff]);
          acc[nt][p] = __builtin_amdgcn_mfma_f32_16x16x32_bf16(ua.v, bh, acc[nt][p], 0, 0, 0);
        }
      }
      // publish foreign partials: nt0 from waves 1,2,3 -> slots 0,1,2;
      //                           nt1 from waves 0,2,3 -> slots 3,4,5.
      f32x4 s0, s1;
      #pragma unroll
      for (int r = 0; r < 4; ++r) {
        s0[r] = acc[0][0][r] + acc[0][1][r];
        s1[r] = acc[1][0][r] + acc[1][1][r];
      }
      if (wid != 0)
        *reinterpret_cast<f32x4*>(&red[((wid - 1) * 64 + lane) * 4]) = s0;
      if (wid != 1)
        *reinterpret_cast<f32x4*>(&red[((3 + (wid == 0 ? 0 : wid - 1)) * 64 + lane) * 4]) = s1;
      __syncthreads();                       // barrier1: red ready
      if (wid < 2) {                         // wave wid reduces nt=wid + tanh
        f32x4 s = (wid == 0) ? s0 : s1;
        int base = wid * 3;
        #pragma unroll
        for (int j = 0; j < 3; ++j) {
          f32x4 rv = *reinterpret_cast<const f32x4*>(&red[((base + j) * 64 + lane) * 4]);
          #pragma unroll
          for (int r = 0; r < 4; ++r) s[r] += rv[r];
        }
        #pragma unroll
        for (int r = 0; r < 4; ++r) {
          float v = s[r] + xpv[r];
          stage[(lk * 4 + r) * 32 + wid * 16 + lr] = tanhf(v);
        }
      }
      __syncthreads();                       // barrier2: stage ready
      // pack h_new -> MALL (hi plane, u64 = 4 elems), 128 threads x 4 elems
      u64* nhq = hhi64 + (size_t)((t + 1) & 1) * 16384;
      if (tid < 128) {
        int idx = tid * 4;
        int cb = idx >> 7, rem = idx & 127, row2 = rem >> 3, e = rem & 7;
        float v0 = stage[row2 * 32 + cb * 8 + e + 0];
        float v1 = stage[row2 * 32 + cb * 8 + e + 1];
        float v2 = stage[row2 * 32 + cb * 8 + e + 2];
        float v3 = stage[row2 * 32 + cb * 8 + e + 3];
        short h0 = f2bf(v0), h1 = f2bf(v1), h2 = f2bf(v2), h3 = f2bf(v3);
        u64 hw = (u64)(uint16_t)h0 | ((u64)(uint16_t)h1 << 16) |
                 ((u64)(uint16_t)h2 << 32) | ((u64)(uint16_t)h3 << 48);
        size_t off = ((size_t)(g * 128 + w * 4 + cb) * 16 + row2) * 2 + (e >> 2);
        astore(nhq + off, hw);
        if (t == TT - 1) {
          size_t o = (size_t)(g * 16 + row2) * 1024 + c0 + cb * 8 + e;
          float4v ov; ov[0] = v0; ov[1] = v1; ov[2] = v2; ov[3] = v3;
          *reinterpret_cast<float4v*>(&out[o]) = ov;
          *reinterpret_cast<float4v*>(&out[65536 + o]) = ov;
        }
      }
      // release: drain sc1 stores, barrier, then ONE flag STORE per WG (no RMW)
      asm volatile("s_waitcnt vmcnt(0)" ::: "memory");
      __syncthreads();
      if (tid == 0)
        __hip_atomic_store(&gflags[w * 16], (unsigned)(t + 1), __ATOMIC_RELAXED,
                           __HIP_MEMORY_SCOPE_AGENT);
    }
  } else {
    // =================== xp GEMM part: [32768 x 1024] = A @ W_ih + bias ======
    short* Ah = (short*)smem;            // 4096 shorts
    short* Al = (short*)(smem + 8192);
    short* Bh = (short*)(smem + 16384);
    short* Bl = (short*)(smem + 24576);

    int b2 = bid - 128;
    int nb = b2 & 7, mb = b2 >> 3;       // t-major: mb = 2 timesteps
    size_t m0 = (size_t)mb * 128;
    int n0 = nb * 128;
    int wm = wid >> 1, wn = wid & 1;
    int lr = lane & 15, lk = lane >> 4;

    f32x4 acc[4][4];
    #pragma unroll
    for (int mt = 0; mt < 4; ++mt)
      #pragma unroll
      for (int nt = 0; nt < 4; ++nt) {
        acc[mt][nt][0] = 0.f; acc[mt][nt][1] = 0.f;
        acc[mt][nt][2] = 0.f; acc[mt][nt][3] = 0.f;
      }

    for (int kt = 0; kt < 32; ++kt) {
      int k0 = kt * 32;
      __syncthreads();
      #pragma unroll
      for (int i = 0; i < 4; ++i) {
        int idx = tid + i * 256;
        int r = idx >> 3, q = idx & 7;
        float4v v = *reinterpret_cast<const float4v*>(&A[(m0 + r) * 1024 + k0 + q * 4]);
        short4v vh, vl;
        #pragma unroll
        for (int j = 0; j < 4; ++j) {
          short h = f2bf(v[j]);
          vh[j] = h;
          vl[j] = f2bf(v[j] - bf2f(h));
        }
        int off = ((q >> 1) * 128 + r) * 8 + (q & 1) * 4;
        *reinterpret_cast<short4v*>(&Ah[off]) = vh;
        *reinterpret_cast<short4v*>(&Al[off]) = vl;
      }
      {
        int n = tid >> 1, half = tid & 1;
        size_t gb = (size_t)(n0 + n) * 1024 + k0 + half * 16;
        bf16x8 h0 = *reinterpret_cast<const bf16x8*>(&ih_hi[gb]);
        bf16x8 h1 = *reinterpret_cast<const bf16x8*>(&ih_hi[gb + 8]);
        bf16x8 l0 = *reinterpret_cast<const bf16x8*>(&ih_lo[gb]);
        bf16x8 l1 = *reinterpret_cast<const bf16x8*>(&ih_lo[gb + 8]);
        int kb = half * 2;
        *reinterpret_cast<bf16x8*>(&Bh[(kb * 128 + n) * 8]) = h0;
        *reinterpret_cast<bf16x8*>(&Bh[((kb + 1) * 128 + n) * 8]) = h1;
        *reinterpret_cast<bf16x8*>(&Bl[(kb * 128 + n) * 8]) = l0;
        *reinterpret_cast<bf16x8*>(&Bl[((kb + 1) * 128 + n) * 8]) = l1;
      }
      __syncthreads();

      bf16x8 a_h[4], a_l[4], b_h[4], b_l[4];
      #pragma unroll
      for (int mt = 0; mt < 4; ++mt) {
        int off = (lk * 128 + wm * 64 + mt * 16 + lr) * 8;
        a_h[mt] = *reinterpret_cast<const bf16x8*>(&Ah[off]);
        a_l[mt] = *reinterpret_cast<const bf16x8*>(&Al[off]);
      }
      #pragma unroll
      for (int nt = 0; nt < 4; ++nt) {
        int off = (lk * 128 + wn * 64 + nt * 16 + lr) * 8;
        b_h[nt] = *reinterpret_cast<const bf16x8*>(&Bh[off]);
        b_l[nt] = *reinterpret_cast<const bf16x8*>(&Bl[off]);
      }
      #pragma unroll
      for (int mt = 0; mt < 4; ++mt)
        #pragma unroll
        for (int nt = 0; nt < 4; ++nt) {
          acc[mt][nt] = __builtin_amdgcn_mfma_f32_16x16x32_bf16(a_h[mt], b_h[nt], acc[mt][nt], 0, 0, 0);
          acc[mt][nt] = __builtin_amdgcn_mfma_f32_16x16x32_bf16(a_h[mt], b_l[nt], acc[mt][nt], 0, 0, 0);
          acc[mt][nt] = __builtin_amdgcn_mfma_f32_16x16x32_bf16(a_l[mt], b_h[nt], acc[mt][nt], 0, 0, 0);
        }
    }
    // epilogue: agent-scope stores (MALL write-through), drain + chunk signal.
    #pragma unroll
    for (int nt = 0; nt < 4; ++nt) {
      int col = n0 + wn * 64 + nt * 16 + lr;
      float bv = bias[col];
      #pragma unroll
      for (int mt = 0; mt < 4; ++mt)
        #pragma unroll
        for (int r = 0; r < 4; ++r) {
          size_t row = m0 + wm * 64 + mt * 16 + lk * 4 + r;
          astoref(&xp[row * 1024 + col], acc[mt][nt][r] + bv);
        }
    }
    asm volatile("s_waitcnt vmcnt(0)" ::: "memory");
    __syncthreads();
    if (tid == 0)
      __hip_atomic_fetch_add(&xpcnt[mb >> 5], 1, __ATOMIC_RELAXED,
                             __HIP_MEMORY_SCOPE_AGENT);
  }
}

extern "C" void kernel_launch(void* const* d_in, const int* in_sizes, int n_in,
                              void* d_out, int out_size, void* d_ws, size_t ws_size,
                              hipStream_t stream) {
  (void)in_sizes; (void)n_in; (void)out_size; (void)ws_size;
  const float* input      = (const float*)d_in[0];
  const float* init_state = (const float*)d_in[1];
  const float* W_ih       = (const float*)d_in[2];
  const float* W_hh       = (const float*)d_in[3];
  const float* bias       = (const float*)d_in[4];
  float* out = (float*)d_out;

  char* ws = (char*)d_ws;
  float* xp = (float*)ws;
  size_t off = (size_t)TT * BB * HH * 4;                 // 134.2 MB x_proj
  short* ih_hi = (short*)(ws + off); off += (size_t)DD * HH * 2;
  short* ih_lo = (short*)(ws + off); off += (size_t)DD * HH * 2;
  short* hh_hi = (short*)(ws + off); off += (size_t)HH * HH * 2;
  short* hh_lo = (short*)(ws + off); off += (size_t)HH * HH * 2;
  u64*   h_hi  = (u64*)(ws + off);   off += (size_t)2 * 16384 * 8;
  unsigned* flags = (unsigned*)(ws + off); off += (size_t)2048 * 4;  // 4 groups x 32 x 16
  int*   xpcnt = (int*)(ws + off);   off += (size_t)16 * 4;

  hipMemsetAsync(flags, 0, 2048 * 4 + 16 * 4, stream);
  k_wsplit<<<512, 256, 0, stream>>>(W_ih, W_hh, ih_hi, ih_lo, hh_hi, hh_lo);
  k_init_h<<<256, 256, 0, stream>>>(init_state, (short*)h_hi);
  k_fused<<<2176, 256, 0, stream>>>(input, ih_hi, ih_lo, bias, hh_hi,
                                    xp, h_hi, flags, xpcnt, out);
}